// Round 6
// baseline (309.843 us; speedup 1.0000x reference)
//
#include <hip/hip_runtime.h>
#include <hip/hip_bf16.h>

#define D_IN  512
#define D_OUT 128
#define FB_SHIFT 7           // fine bucket = 128 rows
#define SB_SHIFT 14          // super bucket = 16384 rows (= 128 fine buckets)
#define NB_S 8
#define MAXFB 800            // >= ceil(100000/128) = 782
#define NFH 800
#define CHUNK 4096
#define CAP2 2560            // bspmm LDS stage capacity (mean 2048, ~11 sigma)
#define MAXE (CAP2 / 256)    // 10 register-held edges per thread

typedef __attribute__((ext_vector_type(8))) short bf16x8;
typedef __attribute__((ext_vector_type(4))) float f32x4;
typedef __attribute__((ext_vector_type(8))) short s16x8;

static __device__ inline short f2bs(float f) {
    __hip_bfloat16 h = __float2bfloat16(f);
    return *reinterpret_cast<short*>(&h);
}

// ---------------------------------------------------------------------------
// prep_hist (heterogeneous grid, 1 dispatch = wt_prep || fhist):
//  blocks [0, nwt):        Wt[n][k] = bf16(W[k][n])
//  blocks [nwt, nwt+nch):  per-chunk fine-bucket LDS hist -> bhist[cb][*]
//                          (non-atomic row store; no global pre-zero needed)
// ---------------------------------------------------------------------------
__global__ __launch_bounds__(256) void prep_hist(
    const float* __restrict__ W, short* __restrict__ Wt,
    const int* __restrict__ row, int* __restrict__ bhist,
    int nnz, int nfb, int nwt)
{
    __shared__ int lh[NFH];
    const int t = threadIdx.x;
    if ((int)blockIdx.x < nwt) {
        int idx = blockIdx.x * 256 + t;
        int k = idx >> 7, c = idx & 127;
        Wt[(long)c * D_IN + k] = f2bs(W[idx]);
        return;
    }
    const int cb = blockIdx.x - nwt;
    for (int i = t; i < nfb; i += 256) lh[i] = 0;
    __syncthreads();
    const int base = cb * CHUNK;
    const int end = min(base + CHUNK, nnz);
    for (int i = base + t; i < end; i += 256)
        atomicAdd(&lh[row[i] >> FB_SHIFT], 1);
    __syncthreads();
    for (int i = t; i < nfb; i += 256)
        bhist[(size_t)cb * NFH + i] = lh[i];
}

// ---------------------------------------------------------------------------
// gemm_fscan (heterogeneous grid):
//  blocks [0, ngemm):  support(bf16) = bf16(x) @ bf16(W) + b
//                      (128x128 tile, BK=32, dbuf, XOR-swizzled LDS)
//  block  ngemm:       fscan -- column-sum bhist rows -> counts, scan ->
//                      foffs / gcursor / scursor  (hidden under gemm)
// ---------------------------------------------------------------------------
__global__ __launch_bounds__(256) void gemm_fscan(
    const float* __restrict__ x,
    const short* __restrict__ Wt,
    const float* __restrict__ b,
    __hip_bfloat16* __restrict__ supb,
    int n_nodes,
    const int* __restrict__ bhist,
    int* __restrict__ foffs,
    int* __restrict__ scursor,
    int* __restrict__ gcursor,
    int nfb, int nnz, int nchunks, int ngemm)
{
    __shared__ s16x8 A_c[2][4 * 128];   // 16KB (aliased as sdata in fscan path)
    __shared__ s16x8 B_c[2][4 * 128];   // 16KB

    const int tid  = threadIdx.x;

    if ((int)blockIdx.x >= ngemm) {
        // ---------------- fscan path (1 block) ----------------
        int* sdata = reinterpret_cast<int*>(A_c);
        const int t = tid;
        int c[4];
        if (t * 4 + 3 < nfb) {
            int4 a4 = make_int4(0, 0, 0, 0);
            for (int cb = 0; cb < nchunks; ++cb) {
                const int4 v = *reinterpret_cast<const int4*>(
                    bhist + (size_t)cb * NFH + t * 4);
                a4.x += v.x; a4.y += v.y; a4.z += v.z; a4.w += v.w;
            }
            c[0] = a4.x; c[1] = a4.y; c[2] = a4.z; c[3] = a4.w;
        } else {
#pragma unroll
            for (int j = 0; j < 4; ++j) {
                int i = t * 4 + j; int s = 0;
                if (i < nfb)
                    for (int cb = 0; cb < nchunks; ++cb)
                        s += bhist[(size_t)cb * NFH + i];
                c[j] = s;
            }
        }
        int s = c[0] + c[1] + c[2] + c[3];
        sdata[t] = s;
        __syncthreads();
        for (int off = 1; off < 256; off <<= 1) {
            int v = (t >= off) ? sdata[t - off] : 0;
            __syncthreads();
            sdata[t] += v;
            __syncthreads();
        }
        int excl = (t == 0) ? 0 : sdata[t - 1];
#pragma unroll
        for (int j = 0; j < 4; ++j) {
            int i = t * 4 + j;
            if (i < nfb) {
                foffs[i] = excl;
                gcursor[i] = excl;
                if ((i & 127) == 0) scursor[i >> 7] = excl;
            }
            excl += c[j];
        }
        if (t == 0) foffs[nfb] = nnz;
        return;
    }

    // ---------------- gemm path ----------------
    const int wave = tid >> 6;
    const int lane = tid & 63;
    const int ln16 = lane & 15;
    const int kb   = lane >> 4;          // 0..3
    const int row0 = blockIdx.x * 128;

    const int srow = tid >> 2;           // 0..63  (j adds 64)
    const int skc  = tid & 3;

    float4 areg[2][2];
    s16x8  breg[2];

    auto load_A = [&](int k0) {
#pragma unroll
        for (int j = 0; j < 2; ++j) {
            int r = row0 + srow + j * 64;
            r = (r < n_nodes) ? r : (n_nodes - 1);
            const float* p = x + (long)r * D_IN + k0 + skc * 8;
            areg[j][0] = *reinterpret_cast<const float4*>(p);
            areg[j][1] = *reinterpret_cast<const float4*>(p + 4);
        }
    };
    auto load_B = [&](int k0) {
#pragma unroll
        for (int j = 0; j < 2; ++j) {
            int c = srow + j * 64;       // col
            breg[j] = *reinterpret_cast<const s16x8*>(Wt + (long)c * D_IN + k0 + skc * 8);
        }
    };
    auto write_AB = [&](int buf) {
#pragma unroll
        for (int j = 0; j < 2; ++j) {
            const int r = srow + j * 64;
            s16x8 v;
            v[0] = f2bs(areg[j][0].x); v[1] = f2bs(areg[j][0].y);
            v[2] = f2bs(areg[j][0].z); v[3] = f2bs(areg[j][0].w);
            v[4] = f2bs(areg[j][1].x); v[5] = f2bs(areg[j][1].y);
            v[6] = f2bs(areg[j][1].z); v[7] = f2bs(areg[j][1].w);
            A_c[buf][skc * 128 + (r ^ skc)] = v;
            B_c[buf][skc * 128 + (r ^ skc)] = breg[j];
        }
    };

    f32x4 acc[2][8];
#pragma unroll
    for (int rg = 0; rg < 2; ++rg)
#pragma unroll
        for (int t = 0; t < 8; ++t) acc[rg][t] = (f32x4){0.f, 0.f, 0.f, 0.f};

    auto compute = [&](int buf) {
        bf16x8 af[2];
#pragma unroll
        for (int rg = 0; rg < 2; ++rg) {
            const int r = wave * 32 + rg * 16 + ln16;
            const s16x8 v = A_c[buf][kb * 128 + (r ^ kb)];
            af[rg] = *reinterpret_cast<const bf16x8*>(&v);
        }
#pragma unroll
        for (int t = 0; t < 8; ++t) {
            const int c = t * 16 + ln16;
            const s16x8 vb = B_c[buf][kb * 128 + (c ^ kb)];
            const bf16x8 bf = *reinterpret_cast<const bf16x8*>(&vb);
            acc[0][t] = __builtin_amdgcn_mfma_f32_16x16x32_bf16(af[0], bf, acc[0][t], 0, 0, 0);
            acc[1][t] = __builtin_amdgcn_mfma_f32_16x16x32_bf16(af[1], bf, acc[1][t], 0, 0, 0);
        }
    };

    load_A(0);
    load_B(0);
    write_AB(0);
    __syncthreads();

    for (int ks = 0; ks < 15; ++ks) {
        const int cur = ks & 1, nxt = cur ^ 1;
        load_A((ks + 1) * 32);
        load_B((ks + 1) * 32);
        compute(cur);
        write_AB(nxt);
        __syncthreads();
    }
    compute(1);

#pragma unroll
    for (int t = 0; t < 8; ++t) {
        const int col = t * 16 + ln16;
        const float bias = b[col];
#pragma unroll
        for (int rg = 0; rg < 2; ++rg) {
#pragma unroll
            for (int r = 0; r < 4; ++r) {
                const int rr = row0 + wave * 32 + rg * 16 + kb * 4 + r;
                if (rr < n_nodes)
                    supb[(long)rr * D_OUT + col] = __float2bfloat16(acc[rg][t][r] + bias);
            }
        }
    }
}

// ---------------------------------------------------------------------------
// Pass A1: build payload int2{ (row&16383)<<17 | col, val } and bin into
// super-buckets (row>>14). All input reads sequential; writes in ~4KB runs.
// ---------------------------------------------------------------------------
__global__ __launch_bounds__(256) void sscatter(
    const int* __restrict__ row, const int* __restrict__ col,
    const float* __restrict__ vals, int* __restrict__ scursor,
    int2* __restrict__ evt, int nnz)
{
    __shared__ int hist[NB_S], lbase[NB_S], gbase[NB_S], lcur[NB_S];
    __shared__ int2 stage[CHUNK];
    const int t = threadIdx.x;
    const int base = blockIdx.x * CHUNK;
    const int nloc = min(CHUNK, nnz - base);
    if (t < NB_S) hist[t] = 0;
    __syncthreads();

    int myr[CHUNK / 256];
#pragma unroll
    for (int j = 0; j < CHUNK / 256; ++j) {
        int e = base + t + j * 256;
        myr[j] = (e < nnz) ? row[e] : -1;
        if (myr[j] >= 0) atomicAdd(&hist[myr[j] >> SB_SHIFT], 1);
    }
    __syncthreads();
    if (t == 0) {
        int run = 0;
#pragma unroll
        for (int s = 0; s < NB_S; ++s) {
            lbase[s] = run; lcur[s] = run;
            int c = hist[s];
            gbase[s] = c ? atomicAdd(&scursor[s], c) : 0;
            run += c;
        }
    }
    __syncthreads();
#pragma unroll
    for (int j = 0; j < CHUNK / 256; ++j) {
        int e = base + t + j * 256;
        if (e < nnz) {
            int slot = atomicAdd(&lcur[myr[j] >> SB_SHIFT], 1);
            stage[slot] = make_int2(((myr[j] & 16383) << 17) | col[e],
                                    __float_as_int(vals[e]));
        }
    }
    __syncthreads();
#pragma unroll
    for (int j = 0; j < CHUNK / 256; ++j) {
        int s = t + j * 256;
        if (s < nloc) {
            int sb = 0;
#pragma unroll
            for (int q = 1; q < NB_S; ++q) if (s >= lbase[q]) sb = q;
            evt[gbase[sb] + (s - lbase[sb])] = stage[s];
        }
    }
}

// ---------------------------------------------------------------------------
// Pass A2: bin payloads into fine buckets. Super id recovered from global
// position via the 9 super boundary offsets; fb = sb*128 + (rl14>>7).
// ---------------------------------------------------------------------------
__global__ __launch_bounds__(256) void fscatter(
    const int2* __restrict__ evt, const int* __restrict__ foffs,
    int* __restrict__ gcursor, int2* __restrict__ ev, int nnz, int nfb)
{
    __shared__ int hist[MAXFB], lbase[MAXFB], gbase[MAXFB];
    __shared__ int ssum[256];
    __shared__ int sbpos[NB_S + 1];
    __shared__ int2 stage[CHUNK];
    __shared__ short sbkt[CHUNK];
    const int t = threadIdx.x;
    const int base = blockIdx.x * CHUNK;
    const int nloc = min(CHUNK, nnz - base);

    for (int i = t; i < nfb; i += 256) hist[i] = 0;
    if (t <= NB_S) {
        int fi = t << 7;
        sbpos[t] = foffs[fi > nfb ? nfb : fi];
    }
    __syncthreads();

    int2 mypay[CHUNK / 256];
    int myfb[CHUNK / 256];
#pragma unroll
    for (int j = 0; j < CHUNK / 256; ++j) {
        int p = base + t + j * 256;
        if (p < nnz) {
            mypay[j] = evt[p];
            int sb = 0;
#pragma unroll
            for (int q = 1; q < NB_S; ++q) if (p >= sbpos[q]) sb = q;
            myfb[j] = sb * 128 + ((mypay[j].x >> 17) >> 7);
            atomicAdd(&hist[myfb[j]], 1);
        } else myfb[j] = -1;
    }
    __syncthreads();

    int c[4], s = 0;
#pragma unroll
    for (int j = 0; j < 4; ++j) {
        int i = t * 4 + j;
        c[j] = (i < nfb) ? hist[i] : 0;
        s += c[j];
    }
    ssum[t] = s;
    __syncthreads();
    for (int off = 1; off < 256; off <<= 1) {
        int v = (t >= off) ? ssum[t - off] : 0;
        __syncthreads();
        ssum[t] += v;
        __syncthreads();
    }
    int excl = (t == 0) ? 0 : ssum[t - 1];
#pragma unroll
    for (int j = 0; j < 4; ++j) {
        int i = t * 4 + j;
        if (i < nfb) {
            lbase[i] = excl;
            gbase[i] = c[j] ? atomicAdd(&gcursor[i], c[j]) : 0;
        }
        excl += c[j];
    }
    __syncthreads();
    for (int i = t; i < nfb; i += 256) hist[i] = lbase[i];
    __syncthreads();

#pragma unroll
    for (int j = 0; j < CHUNK / 256; ++j) {
        if (myfb[j] >= 0) {
            int slot = atomicAdd(&hist[myfb[j]], 1);
            stage[slot] = mypay[j];
            sbkt[slot] = (short)myfb[j];
        }
    }
    __syncthreads();
#pragma unroll
    for (int j = 0; j < CHUNK / 256; ++j) {
        int s2 = t + j * 256;
        if (s2 < nloc) {
            int fb = sbkt[s2];
            ev[gbase[fb] + (s2 - lbase[fb])] = stage[s2];
        }
    }
}

// ---------------------------------------------------------------------------
// bspmm: per 128-row bucket: load bucket edges to registers, build per-row
// counts in LDS, counting-sort to LDS, then 4 waves gather-FMA from LDS.
// ---------------------------------------------------------------------------
__global__ __launch_bounds__(256) void bspmm(
    const int* __restrict__ foffs, const int2* __restrict__ ev,
    const __hip_bfloat16* __restrict__ supb, float* __restrict__ out, int n)
{
    __shared__ int rcnt[128];
    __shared__ int rbase[129];
    __shared__ int lcur[128];
    __shared__ int2 stage[CAP2];
    const int bk = blockIdx.x;
    const int t = threadIdx.x;
    const int r0 = bk << FB_SHIFT;
    const int rend = min(r0 + 128, n);
    const int nrow = rend - r0;
    const int g0 = foffs[bk];
    const int g1 = foffs[bk + 1];
    const int ne = g1 - g0;

    const int w   = t >> 6, l = t & 63;
    const int g   = l >> 4;     // edge slot 0..3
    const int sub = l & 15;     // 8-col sub-block

    if (ne <= CAP2) {
        if (t < 128) rcnt[t] = 0;
        __syncthreads();
        int2 myq[MAXE]; int myrl[MAXE];
#pragma unroll
        for (int j = 0; j < MAXE; ++j) {
            int i = t + j * 256;
            myrl[j] = -1;
            if (i < ne) {
                myq[j] = ev[g0 + i];
                myrl[j] = (myq[j].x >> 17) & 127;
                atomicAdd(&rcnt[myrl[j]], 1);
            }
        }
        __syncthreads();
        if (t < 128) lcur[t] = rcnt[t];
        __syncthreads();
        for (int off = 1; off < 128; off <<= 1) {
            int u = (t < 128 && t >= off) ? lcur[t - off] : 0;
            __syncthreads();
            if (t < 128) lcur[t] += u;
            __syncthreads();
        }
        if (t < 128) rbase[t + 1] = lcur[t];
        if (t == 0) rbase[0] = 0;
        __syncthreads();
        if (t < 128) lcur[t] = rbase[t];
        __syncthreads();
#pragma unroll
        for (int j = 0; j < MAXE; ++j) {
            if (myrl[j] >= 0) {
                int slot = atomicAdd(&lcur[myrl[j]], 1);
                stage[slot] = myq[j];
            }
        }
        __syncthreads();

        for (int rr = w; rr < nrow; rr += 4) {
            const int r = r0 + rr;
            const int e0 = rbase[rr];
            const int e1 = rbase[rr + 1];
            float acc[8];
#pragma unroll
            for (int i = 0; i < 8; ++i) acc[i] = 0.f;

            auto fma_edge = [&](const int2 q) {
                const s16x8 sv = *reinterpret_cast<const s16x8*>(
                    supb + (long)(q.x & 0x1FFFF) * D_OUT + sub * 8);
                const float v = __int_as_float(q.y);
                const __hip_bfloat162* hp = reinterpret_cast<const __hip_bfloat162*>(&sv);
#pragma unroll
                for (int i = 0; i < 4; ++i) {
                    const float2 f = __bfloat1622float2(hp[i]);
                    acc[2 * i]     += v * f.x;
                    acc[2 * i + 1] += v * f.y;
                }
            };

            int e = e0;
            for (; e + 16 <= e1; e += 16) {
                const int2 q0 = stage[e + g];
                const int2 q1 = stage[e + 4 + g];
                const int2 q2 = stage[e + 8 + g];
                const int2 q3 = stage[e + 12 + g];
                fma_edge(q0); fma_edge(q1); fma_edge(q2); fma_edge(q3);
            }
            for (; e + 4 <= e1; e += 4) {
                fma_edge(stage[e + g]);
            }
            const int rem = e1 - e;
            if (g < rem) fma_edge(stage[e + g]);

#pragma unroll
            for (int i = 0; i < 8; ++i) {
                acc[i] += __shfl_xor(acc[i], 16);
                acc[i] += __shfl_xor(acc[i], 32);
            }
            if (g == 0) {
                float4 o0 = make_float4(acc[0], acc[1], acc[2], acc[3]);
                float4 o1 = make_float4(acc[4], acc[5], acc[6], acc[7]);
                float* op = out + (long)r * D_OUT + sub * 8;
                *reinterpret_cast<float4*>(op) = o0;
                *reinterpret_cast<float4*>(op + 4) = o1;
            }
        }
    } else {
        for (int rr = w; rr < nrow; rr += 4) {
            const int r = r0 + rr;
            const int rl = r & 127;
            float ax = 0.f, ay = 0.f;
            for (int e = g0; e < g1; ++e) {
                const int2 q = ev[e];
                if (((q.x >> 17) & 127) == rl) {
                    const float v = __int_as_float(q.y);
                    const __hip_bfloat162 sh = *reinterpret_cast<const __hip_bfloat162*>(
                        supb + (long)(q.x & 0x1FFFF) * D_OUT + l * 2);
                    const float2 f = __bfloat1622float2(sh);
                    ax += v * f.x;
                    ay += v * f.y;
                }
            }
            *reinterpret_cast<float2*>(out + (long)r * D_OUT + l * 2) =
                make_float2(ax, ay);
        }
    }
}

// Fallback (ws too small): atomic spmm
__global__ __launch_bounds__(256) void spmm_atomic(
    const __hip_bfloat16* __restrict__ supb, const float* __restrict__ vals,
    const int* __restrict__ row, const int* __restrict__ col,
    float* __restrict__ out, int nnz)
{
    long gidx = (long)blockIdx.x * 256 + threadIdx.x;
    int e = (int)(gidx >> 7);
    int d = (int)(gidx & 127);
    if (e < nnz) {
        atomicAdd(&out[(long)row[e] * D_OUT + d],
                  vals[e] * __bfloat162float(supb[(long)col[e] * D_OUT + d]));
    }
}

extern "C" void kernel_launch(void* const* d_in, const int* in_sizes, int n_in,
                              void* d_out, int out_size, void* d_ws, size_t ws_size,
                              hipStream_t stream) {
    const float* x    = (const float*)d_in[0];
    const float* W    = (const float*)d_in[1];
    const float* b    = (const float*)d_in[2];
    const float* vals = (const float*)d_in[3];
    const int*   row  = (const int*)d_in[4];
    const int*   col  = (const int*)d_in[5];
    float* out = (float*)d_out;

    const int n_nodes = in_sizes[0] / D_IN;
    const int nnz     = in_sizes[3];
    const int nfb     = (n_nodes + 127) >> FB_SHIFT;
    const int nch     = (nnz + CHUNK - 1) / CHUNK;
    const int nwt     = (D_IN * D_OUT) / 256;       // 256 blocks
    const int ngemm   = (n_nodes + 127) / 128;

    auto align_up = [](size_t v) { return (v + 255) & ~(size_t)255; };
    char* wsb = (char*)d_ws;
    size_t off = 0;
    __hip_bfloat16* supb = (__hip_bfloat16*)(wsb + off);
    off = align_up(off + (size_t)n_nodes * D_OUT * 2);
    short* Wt = (short*)(wsb + off);
    off = align_up(off + (size_t)D_OUT * D_IN * 2);
    const size_t need_fallback = off;
    int* bhist   = (int*)(wsb + off); off = align_up(off + (size_t)nch * NFH * 4);
    int* foffs   = (int*)(wsb + off); off = align_up(off + (size_t)(nfb + 1) * 4);
    int* scursor = (int*)(wsb + off); off = align_up(off + NB_S * 4);
    int* gcursor = (int*)(wsb + off); off = align_up(off + (size_t)nfb * 4);
    int2* evt    = (int2*)(wsb + off); off = align_up(off + (size_t)nnz * 8);
    int2* ev     = (int2*)(wsb + off); off = align_up(off + (size_t)nnz * 8);
    const size_t need_full = off;

    if (ws_size >= need_full && nfb <= MAXFB) {
        // K1: Wt transpose || per-chunk fine histograms
        prep_hist<<<dim3(nwt + nch), dim3(256), 0, stream>>>(
            W, Wt, row, bhist, nnz, nfb, nwt);
        // K2: gemm || fscan (scan hidden under gemm)
        gemm_fscan<<<dim3(ngemm + 1), dim3(256), 0, stream>>>(
            x, Wt, b, supb, n_nodes, bhist, foffs, scursor, gcursor,
            nfb, nnz, nch, ngemm);
        sscatter<<<dim3(nch), dim3(256), 0, stream>>>(
            row, col, vals, scursor, evt, nnz);
        fscatter<<<dim3(nch), dim3(256), 0, stream>>>(
            evt, foffs, gcursor, ev, nnz, nfb);
        bspmm<<<dim3(nfb), dim3(256), 0, stream>>>(foffs, ev, supb, out, n_nodes);
    } else if (ws_size >= need_fallback) {
        // wt only (no fhist blocks), gemm only (no fscan block)
        prep_hist<<<dim3(nwt), dim3(256), 0, stream>>>(
            W, Wt, row, (int*)d_ws, 0, nfb, nwt);
        gemm_fscan<<<dim3(ngemm), dim3(256), 0, stream>>>(
            x, Wt, b, supb, n_nodes, (int*)d_ws, (int*)d_ws, (int*)d_ws,
            (int*)d_ws, nfb, nnz, 0, ngemm);
        hipMemsetAsync(out, 0, (size_t)out_size * 4, stream);
        long total = (long)nnz * D_OUT;
        spmm_atomic<<<dim3((int)((total + 255) / 256)), dim3(256), 0, stream>>>(
            supb, vals, row, col, out, nnz);
    }
}

// Round 7
// 209.371 us; speedup vs baseline: 1.4799x; 1.4799x over previous
//
#include <hip/hip_runtime.h>
#include <hip/hip_bf16.h>

#define D_IN  512
#define D_OUT 128
#define FB_SHIFT 7           // fine bucket = 128 rows
#define SB_SHIFT 14          // super bucket = 16384 rows (= 128 fine buckets)
#define NB_S 8
#define MAXFB 800            // >= ceil(100000/128) = 782
#define NFH 800
#define CHUNK 4096
#define CAP2 2560            // bspmm LDS stage capacity (mean 2048, ~11 sigma)
#define MAXE (CAP2 / 256)    // 10 register-held edges per thread

typedef __attribute__((ext_vector_type(8))) short bf16x8;
typedef __attribute__((ext_vector_type(4))) float f32x4;
typedef __attribute__((ext_vector_type(8))) short s16x8;

static __device__ inline short f2bs(float f) {
    __hip_bfloat16 h = __float2bfloat16(f);
    return *reinterpret_cast<short*>(&h);
}

// ---------------------------------------------------------------------------
// prep_hist (heterogeneous grid, 1 dispatch = wt_prep || fhist):
//  blocks [0, nwt):        Wt[n][k] = bf16(W[k][n])
//  blocks [nwt, nwt+nch):  per-chunk fine-bucket LDS hist -> bhist[cb][*]
//                          FULL NFH width, zero-padded (enables all-vector
//                          reduction in fscan)
// ---------------------------------------------------------------------------
__global__ __launch_bounds__(256) void prep_hist(
    const float* __restrict__ W, short* __restrict__ Wt,
    const int* __restrict__ row, int* __restrict__ bhist,
    int nnz, int nfb, int nwt)
{
    __shared__ int lh[NFH];
    const int t = threadIdx.x;
    if ((int)blockIdx.x < nwt) {
        int idx = blockIdx.x * 256 + t;
        int k = idx >> 7, c = idx & 127;
        Wt[(long)c * D_IN + k] = f2bs(W[idx]);
        return;
    }
    const int cb = blockIdx.x - nwt;
    for (int i = t; i < NFH; i += 256) lh[i] = 0;
    __syncthreads();
    const int base = cb * CHUNK;
    const int end = min(base + CHUNK, nnz);
    for (int i = base + t; i < end; i += 256)
        atomicAdd(&lh[row[i] >> FB_SHIFT], 1);
    __syncthreads();
    for (int i = t; i < NFH; i += 256)
        bhist[(size_t)cb * NFH + i] = lh[i];
}

// ---------------------------------------------------------------------------
// gemm_fscan (heterogeneous grid):
//  blocks [0, ngemm):  support(bf16) = bf16(x) @ bf16(W) + b
//  block  ngemm:       fscan -- 8-way-unrolled column-sum of bhist rows
//                      (8 independent int4 accumulators -> 8 loads in
//                      flight; the round-6 serial chain was 212us), scan
//                      -> foffs / gcursor / scursor  (hidden under gemm)
// ---------------------------------------------------------------------------
__global__ __launch_bounds__(256) void gemm_fscan(
    const float* __restrict__ x,
    const short* __restrict__ Wt,
    const float* __restrict__ b,
    __hip_bfloat16* __restrict__ supb,
    int n_nodes,
    const int* __restrict__ bhist,
    int* __restrict__ foffs,
    int* __restrict__ scursor,
    int* __restrict__ gcursor,
    int nfb, int nnz, int nchunks, int ngemm)
{
    __shared__ s16x8 A_c[2][4 * 128];   // 16KB (aliased as sdata in fscan path)
    __shared__ s16x8 B_c[2][4 * 128];   // 16KB

    const int tid  = threadIdx.x;

    if ((int)blockIdx.x >= ngemm) {
        // ---------------- fscan path (1 block) ----------------
        int* sdata = reinterpret_cast<int*>(A_c);
        const int t = tid;
        int c[4] = {0, 0, 0, 0};
        if (t < NFH / 4) {
            int4 a8[8];
#pragma unroll
            for (int u = 0; u < 8; ++u) a8[u] = make_int4(0, 0, 0, 0);
            const int* bp = bhist + t * 4;
            int cb = 0;
            for (; cb + 8 <= nchunks; cb += 8) {
#pragma unroll
                for (int u = 0; u < 8; ++u) {
                    const int4 v = *reinterpret_cast<const int4*>(
                        bp + (size_t)(cb + u) * NFH);
                    a8[u].x += v.x; a8[u].y += v.y;
                    a8[u].z += v.z; a8[u].w += v.w;
                }
            }
            for (; cb < nchunks; ++cb) {
                const int4 v = *reinterpret_cast<const int4*>(
                    bp + (size_t)cb * NFH);
                a8[0].x += v.x; a8[0].y += v.y;
                a8[0].z += v.z; a8[0].w += v.w;
            }
#pragma unroll
            for (int u = 1; u < 8; ++u) {
                a8[0].x += a8[u].x; a8[0].y += a8[u].y;
                a8[0].z += a8[u].z; a8[0].w += a8[u].w;
            }
            c[0] = a8[0].x; c[1] = a8[0].y; c[2] = a8[0].z; c[3] = a8[0].w;
        }
        int s = c[0] + c[1] + c[2] + c[3];
        sdata[t] = s;
        __syncthreads();
        for (int off = 1; off < 256; off <<= 1) {
            int v = (t >= off) ? sdata[t - off] : 0;
            __syncthreads();
            sdata[t] += v;
            __syncthreads();
        }
        int excl = (t == 0) ? 0 : sdata[t - 1];
#pragma unroll
        for (int j = 0; j < 4; ++j) {
            int i = t * 4 + j;
            if (i < nfb) {
                foffs[i] = excl;
                gcursor[i] = excl;
                if ((i & 127) == 0) scursor[i >> 7] = excl;
            }
            excl += c[j];
        }
        if (t == 0) foffs[nfb] = nnz;
        return;
    }

    // ---------------- gemm path ----------------
    const int wave = tid >> 6;
    const int lane = tid & 63;
    const int ln16 = lane & 15;
    const int kb   = lane >> 4;          // 0..3
    const int row0 = blockIdx.x * 128;

    const int srow = tid >> 2;           // 0..63  (j adds 64)
    const int skc  = tid & 3;

    float4 areg[2][2];
    s16x8  breg[2];

    auto load_A = [&](int k0) {
#pragma unroll
        for (int j = 0; j < 2; ++j) {
            int r = row0 + srow + j * 64;
            r = (r < n_nodes) ? r : (n_nodes - 1);
            const float* p = x + (long)r * D_IN + k0 + skc * 8;
            areg[j][0] = *reinterpret_cast<const float4*>(p);
            areg[j][1] = *reinterpret_cast<const float4*>(p + 4);
        }
    };
    auto load_B = [&](int k0) {
#pragma unroll
        for (int j = 0; j < 2; ++j) {
            int c = srow + j * 64;       // col
            breg[j] = *reinterpret_cast<const s16x8*>(Wt + (long)c * D_IN + k0 + skc * 8);
        }
    };
    auto write_AB = [&](int buf) {
#pragma unroll
        for (int j = 0; j < 2; ++j) {
            const int r = srow + j * 64;
            s16x8 v;
            v[0] = f2bs(areg[j][0].x); v[1] = f2bs(areg[j][0].y);
            v[2] = f2bs(areg[j][0].z); v[3] = f2bs(areg[j][0].w);
            v[4] = f2bs(areg[j][1].x); v[5] = f2bs(areg[j][1].y);
            v[6] = f2bs(areg[j][1].z); v[7] = f2bs(areg[j][1].w);
            A_c[buf][skc * 128 + (r ^ skc)] = v;
            B_c[buf][skc * 128 + (r ^ skc)] = breg[j];
        }
    };

    f32x4 acc[2][8];
#pragma unroll
    for (int rg = 0; rg < 2; ++rg)
#pragma unroll
        for (int t = 0; t < 8; ++t) acc[rg][t] = (f32x4){0.f, 0.f, 0.f, 0.f};

    auto compute = [&](int buf) {
        bf16x8 af[2];
#pragma unroll
        for (int rg = 0; rg < 2; ++rg) {
            const int r = wave * 32 + rg * 16 + ln16;
            const s16x8 v = A_c[buf][kb * 128 + (r ^ kb)];
            af[rg] = *reinterpret_cast<const bf16x8*>(&v);
        }
#pragma unroll
        for (int t = 0; t < 8; ++t) {
            const int c = t * 16 + ln16;
            const s16x8 vb = B_c[buf][kb * 128 + (c ^ kb)];
            const bf16x8 bf = *reinterpret_cast<const bf16x8*>(&vb);
            acc[0][t] = __builtin_amdgcn_mfma_f32_16x16x32_bf16(af[0], bf, acc[0][t], 0, 0, 0);
            acc[1][t] = __builtin_amdgcn_mfma_f32_16x16x32_bf16(af[1], bf, acc[1][t], 0, 0, 0);
        }
    };

    load_A(0);
    load_B(0);
    write_AB(0);
    __syncthreads();

    for (int ks = 0; ks < 15; ++ks) {
        const int cur = ks & 1, nxt = cur ^ 1;
        load_A((ks + 1) * 32);
        load_B((ks + 1) * 32);
        compute(cur);
        write_AB(nxt);
        __syncthreads();
    }
    compute(1);

#pragma unroll
    for (int t = 0; t < 8; ++t) {
        const int col = t * 16 + ln16;
        const float bias = b[col];
#pragma unroll
        for (int rg = 0; rg < 2; ++rg) {
#pragma unroll
            for (int r = 0; r < 4; ++r) {
                const int rr = row0 + wave * 32 + rg * 16 + kb * 4 + r;
                if (rr < n_nodes)
                    supb[(long)rr * D_OUT + col] = __float2bfloat16(acc[rg][t][r] + bias);
            }
        }
    }
}

// ---------------------------------------------------------------------------
// Pass A1: build payload int2{ (row&16383)<<17 | col, val } and bin into
// super-buckets (row>>14). All input reads sequential; writes in ~4KB runs.
// ---------------------------------------------------------------------------
__global__ __launch_bounds__(256) void sscatter(
    const int* __restrict__ row, const int* __restrict__ col,
    const float* __restrict__ vals, int* __restrict__ scursor,
    int2* __restrict__ evt, int nnz)
{
    __shared__ int hist[NB_S], lbase[NB_S], gbase[NB_S], lcur[NB_S];
    __shared__ int2 stage[CHUNK];
    const int t = threadIdx.x;
    const int base = blockIdx.x * CHUNK;
    const int nloc = min(CHUNK, nnz - base);
    if (t < NB_S) hist[t] = 0;
    __syncthreads();

    int myr[CHUNK / 256];
#pragma unroll
    for (int j = 0; j < CHUNK / 256; ++j) {
        int e = base + t + j * 256;
        myr[j] = (e < nnz) ? row[e] : -1;
        if (myr[j] >= 0) atomicAdd(&hist[myr[j] >> SB_SHIFT], 1);
    }
    __syncthreads();
    if (t == 0) {
        int run = 0;
#pragma unroll
        for (int s = 0; s < NB_S; ++s) {
            lbase[s] = run; lcur[s] = run;
            int c = hist[s];
            gbase[s] = c ? atomicAdd(&scursor[s], c) : 0;
            run += c;
        }
    }
    __syncthreads();
#pragma unroll
    for (int j = 0; j < CHUNK / 256; ++j) {
        int e = base + t + j * 256;
        if (e < nnz) {
            int slot = atomicAdd(&lcur[myr[j] >> SB_SHIFT], 1);
            stage[slot] = make_int2(((myr[j] & 16383) << 17) | col[e],
                                    __float_as_int(vals[e]));
        }
    }
    __syncthreads();
#pragma unroll
    for (int j = 0; j < CHUNK / 256; ++j) {
        int s = t + j * 256;
        if (s < nloc) {
            int sb = 0;
#pragma unroll
            for (int q = 1; q < NB_S; ++q) if (s >= lbase[q]) sb = q;
            evt[gbase[sb] + (s - lbase[sb])] = stage[s];
        }
    }
}

// ---------------------------------------------------------------------------
// Pass A2: bin payloads into fine buckets. Super id recovered from global
// position via the 9 super boundary offsets; fb = sb*128 + (rl14>>7).
// ---------------------------------------------------------------------------
__global__ __launch_bounds__(256) void fscatter(
    const int2* __restrict__ evt, const int* __restrict__ foffs,
    int* __restrict__ gcursor, int2* __restrict__ ev, int nnz, int nfb)
{
    __shared__ int hist[MAXFB], lbase[MAXFB], gbase[MAXFB];
    __shared__ int ssum[256];
    __shared__ int sbpos[NB_S + 1];
    __shared__ int2 stage[CHUNK];
    __shared__ short sbkt[CHUNK];
    const int t = threadIdx.x;
    const int base = blockIdx.x * CHUNK;
    const int nloc = min(CHUNK, nnz - base);

    for (int i = t; i < nfb; i += 256) hist[i] = 0;
    if (t <= NB_S) {
        int fi = t << 7;
        sbpos[t] = foffs[fi > nfb ? nfb : fi];
    }
    __syncthreads();

    int2 mypay[CHUNK / 256];
    int myfb[CHUNK / 256];
#pragma unroll
    for (int j = 0; j < CHUNK / 256; ++j) {
        int p = base + t + j * 256;
        if (p < nnz) {
            mypay[j] = evt[p];
            int sb = 0;
#pragma unroll
            for (int q = 1; q < NB_S; ++q) if (p >= sbpos[q]) sb = q;
            myfb[j] = sb * 128 + ((mypay[j].x >> 17) >> 7);
            atomicAdd(&hist[myfb[j]], 1);
        } else myfb[j] = -1;
    }
    __syncthreads();

    int c[4], s = 0;
#pragma unroll
    for (int j = 0; j < 4; ++j) {
        int i = t * 4 + j;
        c[j] = (i < nfb) ? hist[i] : 0;
        s += c[j];
    }
    ssum[t] = s;
    __syncthreads();
    for (int off = 1; off < 256; off <<= 1) {
        int v = (t >= off) ? ssum[t - off] : 0;
        __syncthreads();
        ssum[t] += v;
        __syncthreads();
    }
    int excl = (t == 0) ? 0 : ssum[t - 1];
#pragma unroll
    for (int j = 0; j < 4; ++j) {
        int i = t * 4 + j;
        if (i < nfb) {
            lbase[i] = excl;
            gbase[i] = c[j] ? atomicAdd(&gcursor[i], c[j]) : 0;
        }
        excl += c[j];
    }
    __syncthreads();
    for (int i = t; i < nfb; i += 256) hist[i] = lbase[i];
    __syncthreads();

#pragma unroll
    for (int j = 0; j < CHUNK / 256; ++j) {
        if (myfb[j] >= 0) {
            int slot = atomicAdd(&hist[myfb[j]], 1);
            stage[slot] = mypay[j];
            sbkt[slot] = (short)myfb[j];
        }
    }
    __syncthreads();
#pragma unroll
    for (int j = 0; j < CHUNK / 256; ++j) {
        int s2 = t + j * 256;
        if (s2 < nloc) {
            int fb = sbkt[s2];
            ev[gbase[fb] + (s2 - lbase[fb])] = stage[s2];
        }
    }
}

// ---------------------------------------------------------------------------
// bspmm: per 128-row bucket: load bucket edges to registers, build per-row
// counts in LDS, counting-sort to LDS, then 4 waves gather-FMA from LDS.
// ---------------------------------------------------------------------------
__global__ __launch_bounds__(256) void bspmm(
    const int* __restrict__ foffs, const int2* __restrict__ ev,
    const __hip_bfloat16* __restrict__ supb, float* __restrict__ out, int n)
{
    __shared__ int rcnt[128];
    __shared__ int rbase[129];
    __shared__ int lcur[128];
    __shared__ int2 stage[CAP2];
    const int bk = blockIdx.x;
    const int t = threadIdx.x;
    const int r0 = bk << FB_SHIFT;
    const int rend = min(r0 + 128, n);
    const int nrow = rend - r0;
    const int g0 = foffs[bk];
    const int g1 = foffs[bk + 1];
    const int ne = g1 - g0;

    const int w   = t >> 6, l = t & 63;
    const int g   = l >> 4;     // edge slot 0..3
    const int sub = l & 15;     // 8-col sub-block

    if (ne <= CAP2) {
        if (t < 128) rcnt[t] = 0;
        __syncthreads();
        int2 myq[MAXE]; int myrl[MAXE];
#pragma unroll
        for (int j = 0; j < MAXE; ++j) {
            int i = t + j * 256;
            myrl[j] = -1;
            if (i < ne) {
                myq[j] = ev[g0 + i];
                myrl[j] = (myq[j].x >> 17) & 127;
                atomicAdd(&rcnt[myrl[j]], 1);
            }
        }
        __syncthreads();
        if (t < 128) lcur[t] = rcnt[t];
        __syncthreads();
        for (int off = 1; off < 128; off <<= 1) {
            int u = (t < 128 && t >= off) ? lcur[t - off] : 0;
            __syncthreads();
            if (t < 128) lcur[t] += u;
            __syncthreads();
        }
        if (t < 128) rbase[t + 1] = lcur[t];
        if (t == 0) rbase[0] = 0;
        __syncthreads();
        if (t < 128) lcur[t] = rbase[t];
        __syncthreads();
#pragma unroll
        for (int j = 0; j < MAXE; ++j) {
            if (myrl[j] >= 0) {
                int slot = atomicAdd(&lcur[myrl[j]], 1);
                stage[slot] = myq[j];
            }
        }
        __syncthreads();

        for (int rr = w; rr < nrow; rr += 4) {
            const int r = r0 + rr;
            const int e0 = rbase[rr];
            const int e1 = rbase[rr + 1];
            float acc[8];
#pragma unroll
            for (int i = 0; i < 8; ++i) acc[i] = 0.f;

            auto fma_edge = [&](const int2 q) {
                const s16x8 sv = *reinterpret_cast<const s16x8*>(
                    supb + (long)(q.x & 0x1FFFF) * D_OUT + sub * 8);
                const float v = __int_as_float(q.y);
                const __hip_bfloat162* hp = reinterpret_cast<const __hip_bfloat162*>(&sv);
#pragma unroll
                for (int i = 0; i < 4; ++i) {
                    const float2 f = __bfloat1622float2(hp[i]);
                    acc[2 * i]     += v * f.x;
                    acc[2 * i + 1] += v * f.y;
                }
            };

            int e = e0;
            for (; e + 16 <= e1; e += 16) {
                const int2 q0 = stage[e + g];
                const int2 q1 = stage[e + 4 + g];
                const int2 q2 = stage[e + 8 + g];
                const int2 q3 = stage[e + 12 + g];
                fma_edge(q0); fma_edge(q1); fma_edge(q2); fma_edge(q3);
            }
            for (; e + 4 <= e1; e += 4) {
                fma_edge(stage[e + g]);
            }
            const int rem = e1 - e;
            if (g < rem) fma_edge(stage[e + g]);

#pragma unroll
            for (int i = 0; i < 8; ++i) {
                acc[i] += __shfl_xor(acc[i], 16);
                acc[i] += __shfl_xor(acc[i], 32);
            }
            if (g == 0) {
                float4 o0 = make_float4(acc[0], acc[1], acc[2], acc[3]);
                float4 o1 = make_float4(acc[4], acc[5], acc[6], acc[7]);
                float* op = out + (long)r * D_OUT + sub * 8;
                *reinterpret_cast<float4*>(op) = o0;
                *reinterpret_cast<float4*>(op + 4) = o1;
            }
        }
    } else {
        for (int rr = w; rr < nrow; rr += 4) {
            const int r = r0 + rr;
            const int rl = r & 127;
            float ax = 0.f, ay = 0.f;
            for (int e = g0; e < g1; ++e) {
                const int2 q = ev[e];
                if (((q.x >> 17) & 127) == rl) {
                    const float v = __int_as_float(q.y);
                    const __hip_bfloat162 sh = *reinterpret_cast<const __hip_bfloat162*>(
                        supb + (long)(q.x & 0x1FFFF) * D_OUT + l * 2);
                    const float2 f = __bfloat1622float2(sh);
                    ax += v * f.x;
                    ay += v * f.y;
                }
            }
            *reinterpret_cast<float2*>(out + (long)r * D_OUT + l * 2) =
                make_float2(ax, ay);
        }
    }
}

// Fallback (ws too small): atomic spmm
__global__ __launch_bounds__(256) void spmm_atomic(
    const __hip_bfloat16* __restrict__ supb, const float* __restrict__ vals,
    const int* __restrict__ row, const int* __restrict__ col,
    float* __restrict__ out, int nnz)
{
    long gidx = (long)blockIdx.x * 256 + threadIdx.x;
    int e = (int)(gidx >> 7);
    int d = (int)(gidx & 127);
    if (e < nnz) {
        atomicAdd(&out[(long)row[e] * D_OUT + d],
                  vals[e] * __bfloat162float(supb[(long)col[e] * D_OUT + d]));
    }
}

extern "C" void kernel_launch(void* const* d_in, const int* in_sizes, int n_in,
                              void* d_out, int out_size, void* d_ws, size_t ws_size,
                              hipStream_t stream) {
    const float* x    = (const float*)d_in[0];
    const float* W    = (const float*)d_in[1];
    const float* b    = (const float*)d_in[2];
    const float* vals = (const float*)d_in[3];
    const int*   row  = (const int*)d_in[4];
    const int*   col  = (const int*)d_in[5];
    float* out = (float*)d_out;

    const int n_nodes = in_sizes[0] / D_IN;
    const int nnz     = in_sizes[3];
    const int nfb     = (n_nodes + 127) >> FB_SHIFT;
    const int nch     = (nnz + CHUNK - 1) / CHUNK;
    const int nwt     = (D_IN * D_OUT) / 256;       // 256 blocks
    const int ngemm   = (n_nodes + 127) / 128;

    auto align_up = [](size_t v) { return (v + 255) & ~(size_t)255; };
    char* wsb = (char*)d_ws;
    size_t off = 0;
    __hip_bfloat16* supb = (__hip_bfloat16*)(wsb + off);
    off = align_up(off + (size_t)n_nodes * D_OUT * 2);
    short* Wt = (short*)(wsb + off);
    off = align_up(off + (size_t)D_OUT * D_IN * 2);
    const size_t need_fallback = off;
    int* bhist   = (int*)(wsb + off); off = align_up(off + (size_t)nch * NFH * 4);
    int* foffs   = (int*)(wsb + off); off = align_up(off + (size_t)(nfb + 1) * 4);
    int* scursor = (int*)(wsb + off); off = align_up(off + NB_S * 4);
    int* gcursor = (int*)(wsb + off); off = align_up(off + (size_t)nfb * 4);
    int2* evt    = (int2*)(wsb + off); off = align_up(off + (size_t)nnz * 8);
    int2* ev     = (int2*)(wsb + off); off = align_up(off + (size_t)nnz * 8);
    const size_t need_full = off;

    if (ws_size >= need_full && nfb <= MAXFB) {
        // K1: Wt transpose || per-chunk fine histograms
        prep_hist<<<dim3(nwt + nch), dim3(256), 0, stream>>>(
            W, Wt, row, bhist, nnz, nfb, nwt);
        // K2: gemm || fscan (ILP-unrolled scan hidden under gemm)
        gemm_fscan<<<dim3(ngemm + 1), dim3(256), 0, stream>>>(
            x, Wt, b, supb, n_nodes, bhist, foffs, scursor, gcursor,
            nfb, nnz, nch, ngemm);
        sscatter<<<dim3(nch), dim3(256), 0, stream>>>(
            row, col, vals, scursor, evt, nnz);
        fscatter<<<dim3(nch), dim3(256), 0, stream>>>(
            evt, foffs, gcursor, ev, nnz, nfb);
        bspmm<<<dim3(nfb), dim3(256), 0, stream>>>(foffs, ev, supb, out, n_nodes);
    } else if (ws_size >= need_fallback) {
        // wt only (no fhist blocks), gemm only (no fscan block)
        prep_hist<<<dim3(nwt), dim3(256), 0, stream>>>(
            W, Wt, row, (int*)d_ws, 0, nfb, nwt);
        gemm_fscan<<<dim3(ngemm), dim3(256), 0, stream>>>(
            x, Wt, b, supb, n_nodes, (int*)d_ws, (int*)d_ws, (int*)d_ws,
            (int*)d_ws, nfb, nnz, 0, ngemm);
        hipMemsetAsync(out, 0, (size_t)out_size * 4, stream);
        long total = (long)nnz * D_OUT;
        spmm_atomic<<<dim3((int)((total + 255) / 256)), dim3(256), 0, stream>>>(
            supb, vals, row, col, out, nnz);
    }
}